// Round 6
// baseline (247.665 us; speedup 1.0000x reference)
//
#include <hip/hip_runtime.h>

// GlobalGatedUpdater, round 9: two-kernel split — pure fill-clone broadcast +
// tiny touched-row fixup.
//
// Ledger R3-R8: store rate pinned at 1.8-2.3 TB/s across burst size (1-20 KB),
// stream count (1-16), NT flags, rotation, traffic (218-410 MB). NT refuted
// the L2 write-allocate theory (and the 6.7 TB/s fill uses plain stores
// anyway). The one untested axis: every variant carried an LDS/atomic/branch
// prologue and per-store branching INSIDE the stream. This round isolates the
// store stream itself:
//   kernel 1 (ggu_bcast): thread g reads emb[g] (one coalesced float4) and
//     issues 16 constant-stride stores. No LDS, no nodes, no branches --
//     instruction stream shape == fillBufferAligned.
//   kernel 2 (ggu_fix): 16 blocks; block b re-blends its graph's <=50 touched
//     rows ((1-a)*emb + a*feat), last-write-wins resolved by an is-last scan.
//     ~800 rows x 256 B = 0.1% of output. Stream order serializes the pair.
// If this is STILL ~93 us, the 16-way strided broadcast write is HW-pinned
// and R3 was the roofline.

#define DIM 64
#define SEGS (DIM / 4)          // 16 float4 per row
#define BLOCK 256

typedef float vf4 __attribute__((ext_vector_type(4)));

template <int CB>  // CB = compile-time B (0 = runtime fallback)
__global__ __launch_bounds__(BLOCK) void ggu_bcast(
    const vf4* __restrict__ emb,          // (items*SEGS)
    vf4* __restrict__ out,                // (B, items*SEGS)
    size_t rowsF4, int Brt)
{
    const int B = (CB > 0) ? CB : Brt;
    const size_t g = (size_t)blockIdx.x * BLOCK + threadIdx.x;
    if (g >= rowsF4) return;
    const vf4 v = emb[g];
    vf4* o = out + g;
    if (CB > 0) {
        #pragma unroll
        for (int b = 0; b < CB; ++b) o[(size_t)b * rowsF4] = v;
    } else {
        for (int b = 0; b < B; ++b) o[(size_t)b * rowsF4] = v;
    }
}

// Block b: for each j with no later duplicate (last-write-wins), write
// out[b, nodes[b*n+j], :] = (1-alpha)*emb + alpha*feat[b*n+j].
__global__ __launch_bounds__(BLOCK) void ggu_fix(
    const int* __restrict__ nodes,        // (B*n)
    const float* __restrict__ feat,       // (B*n, DIM)
    const float* __restrict__ emb,        // (items, DIM)
    const float* __restrict__ alpha,      // (items)
    float* __restrict__ out,              // (B, items, DIM)
    int items, int n)
{
    const int b  = blockIdx.x;
    const int jt = threadIdx.x >> 6;      // 0..3  (4 j-lanes)
    const int d  = threadIdx.x & 63;      // feature dim
    const int NJ = BLOCK / 64;            // 4

    __shared__ int ids[256];              // n <= 256 (here n = 50)
    for (int t = threadIdx.x; t < n && t < 256; t += BLOCK)
        ids[t] = nodes[b * n + t];
    __syncthreads();

    for (int j0 = 0; j0 < n; j0 += NJ) {
        const int j = j0 + jt;
        if (j < n) {
            const int row = (n <= 256) ? ids[j] : nodes[b * n + j];
            bool last = true;
            for (int j2 = j + 1; j2 < n; ++j2) {
                const int r2 = (n <= 256) ? ids[j2] : nodes[b * n + j2];
                last &= (r2 != row);
            }
            if (last) {
                const float a = alpha[row];
                const float e = emb[(size_t)row * DIM + d];
                const float f = feat[(size_t)(b * n + j) * DIM + d];
                out[(size_t)b * items * DIM + (size_t)row * DIM + d] =
                    (1.0f - a) * e + a * f;
            }
        }
    }
}

extern "C" void kernel_launch(void* const* d_in, const int* in_sizes, int n_in,
                              void* d_out, int out_size, void* d_ws, size_t ws_size,
                              hipStream_t stream) {
    const int*   nodes = (const int*)d_in[0];
    const float* feat  = (const float*)d_in[1];
    const float* emb   = (const float*)d_in[2];
    const float* alpha = (const float*)d_in[3];

    const int items = in_sizes[3];                 // 50000
    const int B     = out_size / (items * DIM);    // 16
    const int n     = in_sizes[0] / B;             // 50

    const size_t rowsF4 = (size_t)items * SEGS;    // 800000
    const unsigned grid1 = (unsigned)((rowsF4 + BLOCK - 1) / BLOCK);  // 3125

    if (B == 16) {
        ggu_bcast<16><<<grid1, BLOCK, 0, stream>>>(
            (const vf4*)emb, (vf4*)d_out, rowsF4, B);
    } else {
        ggu_bcast<0><<<grid1, BLOCK, 0, stream>>>(
            (const vf4*)emb, (vf4*)d_out, rowsF4, B);
    }
    ggu_fix<<<B, BLOCK, 0, stream>>>(
        nodes, feat, emb, alpha, (float*)d_out, items, n);
}